// Round 9
// baseline (521.623 us; speedup 1.0000x reference)
//
#include <hip/hip_runtime.h>
#include <hip/hip_bf16.h>

#define NU 50000
#define NI 150000
#define NN 200000
#define NE 1250000
#define DD 64
#define NLAYERS 3
#define SCAN_B 1024
#define NB ((NN + SCAN_B - 1) / SCAN_B)   // 196
#define BT_STRIDE 232                      // bf16; 464B row: 16B-aligned, <=2-way banks on frag reads
#define SETUP_BLKS 12500                   // NN*16/256
#define HIST_BLKS ((NE + 255) / 256)       // 4883

typedef __attribute__((ext_vector_type(8))) short bf16x8;
typedef __attribute__((ext_vector_type(4))) float f32x4;

static __device__ __forceinline__ unsigned short f2b(float x) {
  __hip_bfloat16 h = __float2bfloat16(x);  // RNE
  return *reinterpret_cast<unsigned short*>(&h);
}

static __device__ __forceinline__ unsigned int pack2(float lo, float hi) {
  return (unsigned int)f2b(lo) | ((unsigned int)f2b(hi) << 16);
}

static __device__ __forceinline__ float blo(unsigned int u) { return __uint_as_float(u << 16); }
static __device__ __forceinline__ float bhi(unsigned int u) { return __uint_as_float(u & 0xffff0000u); }

// elementwise bf16x8 * bf16x8 -> bf16x8 (via f32)
static __device__ __forceinline__ bf16x8 mulbf8(bf16x8 a, bf16x8 b) {
  union { bf16x8 v; unsigned int u[4]; } A, B, R;
  A.v = a; B.v = b;
#pragma unroll
  for (int i = 0; i < 4; ++i) {
    R.u[i] = pack2(blo(A.u[i]) * blo(B.u[i]), bhi(A.u[i]) * bhi(B.u[i]));
  }
  return R.v;
}

// ---- zero cnt (must precede merged setup+hist launch) ----
__global__ __launch_bounds__(256) void k_zero(int* __restrict__ p) {
  int i = blockIdx.x * 256 + threadIdx.x;
  if (i < NN) p[i] = 0;
}

// ---- merged: init out/ebf + W^T prep (blocks < SETUP_BLKS) | histogram (rest) ----
__global__ __launch_bounds__(256) void k_setup_hist(const float4* __restrict__ ue,
                                                    const float4* __restrict__ ie,
                                                    float4* __restrict__ out4,
                                                    uint2* __restrict__ ebf2,
                                                    const float* __restrict__ Ws,
                                                    unsigned short* __restrict__ WtBf,
                                                    const int* __restrict__ dst,
                                                    int* __restrict__ cnt) {
  int bid = blockIdx.x;
  if (bid < SETUP_BLKS) {
    int gid = bid * 256 + threadIdx.x;  // < NN*16 exactly
    int row = gid >> 4, q = gid & 15;
    float4 v = (row < NU) ? ue[(size_t)row * 16 + q] : ie[(size_t)(row - NU) * 16 + q];
    out4[(size_t)row * 64 + q] = v;  // out row stride = 256 floats = 64 float4
    uint2 b; b.x = pack2(v.x, v.y); b.y = pack2(v.z, v.w);
    ebf2[(size_t)row * 16 + q] = b;  // ebf row = 64 bf16 = 16 uint2
    if (gid < 3 * 64 * 192) {
      int j = gid % 192;
      int n = (gid / 192) & 63;
      int lyr = gid / (192 * 64);
      WtBf[gid] = f2b(Ws[((size_t)lyr * 3 + (j >> 6)) * 4096 + (size_t)(j & 63) * 64 + n]);
    }
  } else {
    int e = (bid - SETUP_BLKS) * 256 + threadIdx.x;
    if (e < NE) atomicAdd(&cnt[dst[e]], 1);
  }
}

__global__ __launch_bounds__(SCAN_B) void k_scan1(const int* __restrict__ cnt,
                                                  int* __restrict__ local,
                                                  int* __restrict__ btot) {
  __shared__ int sm[SCAN_B];
  int t = threadIdx.x;
  int i = blockIdx.x * SCAN_B + t;
  int v = (i < NN) ? cnt[i] : 0;
  sm[t] = v;
  __syncthreads();
  for (int off = 1; off < SCAN_B; off <<= 1) {
    int x = (t >= off) ? sm[t - off] : 0;
    __syncthreads();
    sm[t] += x;
    __syncthreads();
  }
  if (i < NN) local[i] = sm[t] - v;              // exclusive within block
  if (t == SCAN_B - 1) btot[blockIdx.x] = sm[t]; // block total
}

__global__ __launch_bounds__(256) void k_scan2(int* __restrict__ btot) {
  __shared__ int sm[256];
  int t = threadIdx.x;
  int v = (t < NB) ? btot[t] : 0;
  sm[t] = v;
  __syncthreads();
  for (int off = 1; off < 256; off <<= 1) {
    int x = (t >= off) ? sm[t - off] : 0;
    __syncthreads();
    sm[t] += x;
    __syncthreads();
  }
  if (t < NB) btot[t] = sm[t] - v;  // exclusive block offsets
}

__global__ __launch_bounds__(256) void k_finalize(const int* __restrict__ local,
                                                  const int* __restrict__ btot,
                                                  int* __restrict__ row_start,
                                                  int* __restrict__ cursor) {
  int i = blockIdx.x * 256 + threadIdx.x;
  if (i < NN) {
    int v = local[i] + btot[i / SCAN_B];
    row_start[i] = v;
    cursor[i] = v;
  }
  if (i == 0) row_start[NN] = NE;
}

__global__ __launch_bounds__(256) void k_fill(const int* __restrict__ src,
                                              const int* __restrict__ dst,
                                              const float* __restrict__ w,
                                              int* __restrict__ cursor,
                                              int2* __restrict__ csr_pack) {
  int e = blockIdx.x * 256 + threadIdx.x;
  if (e < NE) {
    int p = atomicAdd(&cursor[dst[e]], 1);
    int2 pk; pk.x = src[e]; pk.y = __float_as_int(w[e]);
    csr_pack[p] = pk;
  }
}

// ---- fused layer: 16 waves, ONE row gathered per wave (full TLP) -> LDS t1 tile ->
//      waves 0-3 do the 16-row MFMA tile (cols split across waves) + leaky + l2norm ----
// block = 1024 thr; grid = 12500 (NN/16 exact); 2 blocks/CU
__global__ __launch_bounds__(1024, 8) void k_layer(const int* __restrict__ row_start,
                                                   const int2* __restrict__ csr_pack,
                                                   const unsigned int* __restrict__ ebf,   // [NN][32] uint
                                                   const unsigned short* __restrict__ WtBf,
                                                   const float* __restrict__ bs,
                                                   float* __restrict__ out,
                                                   unsigned short* __restrict__ ebf_next,
                                                   int layer, int wbf) {
  __shared__ unsigned short Bt[64][BT_STRIDE];  // Bt[n][j] = bf16(Wcat[j][n])
  __shared__ unsigned short t1s[16][72];        // one t1 row per wave (144B stride, 16B-aligned)
  __shared__ float rsum[4][16];                 // per-wave partial row sum-of-squares

  const int tid = threadIdx.x;
  const int wv = tid >> 6;
  const int l = tid & 63;

  {  // stage 24KB Bt tile, fully coalesced
    const uint4* __restrict__ src = reinterpret_cast<const uint4*>(WtBf + (size_t)layer * 64 * 192);
    for (int ch = tid; ch < 1536; ch += 1024) {
      int rown = ch / 24, k = ch % 24;
      *reinterpret_cast<uint4*>(&Bt[rown][k * 8]) = src[ch];
    }
  }

  // ===== gather phase: this wave's row =====
  {
    const int row = blockIdx.x * 16 + wv;
    const int eidx = l >> 3;
    const int cb = l & 7;
    int s0 = row_start[row];
    int s1 = row_start[row + 1];
    int deg = s1 - s0;  // wave-uniform

    float a0 = 0.f, a1 = 0.f, a2 = 0.f, a3 = 0.f, a4 = 0.f, a5 = 0.f, a6 = 0.f, a7 = 0.f;

    if (deg > 0) {
      int j0 = s0 + eidx;
      bool e0 = j0 < s1;
      j0 = e0 ? j0 : s1 - 1;
      int2 p0 = csr_pack[j0];
      uint4 v0 = *reinterpret_cast<const uint4*>(ebf + (size_t)p0.x * 32 + cb * 4);
      float w0 = e0 ? __int_as_float(p0.y) : 0.f;
      if (deg > 8) {
        int j1 = s0 + 8 + eidx;
        bool e1 = j1 < s1;
        j1 = e1 ? j1 : s1 - 1;
        int2 p1 = csr_pack[j1];
        uint4 v1 = *reinterpret_cast<const uint4*>(ebf + (size_t)p1.x * 32 + cb * 4);
        float w1 = e1 ? __int_as_float(p1.y) : 0.f;
        a0 = fmaf(w0, blo(v0.x), a0); a1 = fmaf(w0, bhi(v0.x), a1);
        a2 = fmaf(w0, blo(v0.y), a2); a3 = fmaf(w0, bhi(v0.y), a3);
        a4 = fmaf(w0, blo(v0.z), a4); a5 = fmaf(w0, bhi(v0.z), a5);
        a6 = fmaf(w0, blo(v0.w), a6); a7 = fmaf(w0, bhi(v0.w), a7);
        a0 = fmaf(w1, blo(v1.x), a0); a1 = fmaf(w1, bhi(v1.x), a1);
        a2 = fmaf(w1, blo(v1.y), a2); a3 = fmaf(w1, bhi(v1.y), a3);
        a4 = fmaf(w1, blo(v1.z), a4); a5 = fmaf(w1, bhi(v1.z), a5);
        a6 = fmaf(w1, blo(v1.w), a6); a7 = fmaf(w1, bhi(v1.w), a7);
        for (int base = s0 + 16; base < s1; base += 8) {  // deg>16: ~0.3%
          int j = base + eidx;
          bool ev = j < s1;
          j = ev ? j : s1 - 1;
          int2 p = csr_pack[j];
          uint4 v = *reinterpret_cast<const uint4*>(ebf + (size_t)p.x * 32 + cb * 4);
          float wt = ev ? __int_as_float(p.y) : 0.f;
          a0 = fmaf(wt, blo(v.x), a0); a1 = fmaf(wt, bhi(v.x), a1);
          a2 = fmaf(wt, blo(v.y), a2); a3 = fmaf(wt, bhi(v.y), a3);
          a4 = fmaf(wt, blo(v.z), a4); a5 = fmaf(wt, bhi(v.z), a5);
          a6 = fmaf(wt, blo(v.w), a6); a7 = fmaf(wt, bhi(v.w), a7);
        }
      } else {
        a0 = fmaf(w0, blo(v0.x), a0); a1 = fmaf(w0, bhi(v0.x), a1);
        a2 = fmaf(w0, blo(v0.y), a2); a3 = fmaf(w0, bhi(v0.y), a3);
        a4 = fmaf(w0, blo(v0.z), a4); a5 = fmaf(w0, bhi(v0.z), a5);
        a6 = fmaf(w0, blo(v0.w), a6); a7 = fmaf(w0, bhi(v0.w), a7);
      }
    }

    a0 += __shfl_xor(a0, 8, 64);  a0 += __shfl_xor(a0, 16, 64);  a0 += __shfl_xor(a0, 32, 64);
    a1 += __shfl_xor(a1, 8, 64);  a1 += __shfl_xor(a1, 16, 64);  a1 += __shfl_xor(a1, 32, 64);
    a2 += __shfl_xor(a2, 8, 64);  a2 += __shfl_xor(a2, 16, 64);  a2 += __shfl_xor(a2, 32, 64);
    a3 += __shfl_xor(a3, 8, 64);  a3 += __shfl_xor(a3, 16, 64);  a3 += __shfl_xor(a3, 32, 64);
    a4 += __shfl_xor(a4, 8, 64);  a4 += __shfl_xor(a4, 16, 64);  a4 += __shfl_xor(a4, 32, 64);
    a5 += __shfl_xor(a5, 8, 64);  a5 += __shfl_xor(a5, 16, 64);  a5 += __shfl_xor(a5, 32, 64);
    a6 += __shfl_xor(a6, 8, 64);  a6 += __shfl_xor(a6, 16, 64);  a6 += __shfl_xor(a6, 32, 64);
    a7 += __shfl_xor(a7, 8, 64);  a7 += __shfl_xor(a7, 16, 64);  a7 += __shfl_xor(a7, 32, 64);

    if (l < 8) {
      uint4 st;
      st.x = pack2(a0, a1); st.y = pack2(a2, a3); st.z = pack2(a4, a5); st.w = pack2(a6, a7);
      *reinterpret_cast<uint4*>(&t1s[wv][l * 8]) = st;
    }
  }
  __syncthreads();  // t1 tile + Bt ready

  // ===== MFMA phase: waves 0-3, wave wv handles output cols 16wv..16wv+15 =====
  const int g = l >> 4;    // A: k-group; D: row-group
  const int li = l & 15;   // A: row; D: col-within-block
  f32x4 acc = (f32x4){0.f, 0.f, 0.f, 0.f};
  if (wv < 4) {
    const int r = blockIdx.x * 16 + li;
    bf16x8 A0 = *reinterpret_cast<const bf16x8*>(&t1s[li][8 * g]);
    bf16x8 A1 = *reinterpret_cast<const bf16x8*>(&t1s[li][32 + 8 * g]);
    const unsigned short* __restrict__ eb = reinterpret_cast<const unsigned short*>(ebf);
    bf16x8 E0 = *reinterpret_cast<const bf16x8*>(eb + (size_t)r * 64 + 8 * g);
    bf16x8 E1 = *reinterpret_cast<const bf16x8*>(eb + (size_t)r * 64 + 32 + 8 * g);
    bf16x8 T0 = mulbf8(A0, E0);
    bf16x8 T1 = mulbf8(A1, E1);

    const float* __restrict__ bsl = bs + (size_t)layer * 3 * 64;
    int n = wv * 16 + li;
    float bv = bsl[n] + bsl[64 + n] + bsl[128 + n];
    acc = (f32x4){bv, bv, bv, bv};

    bf16x8 Afr[6] = {A0, A1, T0, T1, E0, E1};
#pragma unroll
    for (int s = 0; s < 6; ++s) {
      const bf16x8 Bf = *reinterpret_cast<const bf16x8*>(&Bt[wv * 16 + li][s * 32 + 8 * g]);
      acc = __builtin_amdgcn_mfma_f32_16x16x32_bf16(Afr[s], Bf, acc, 0, 0, 0);
    }

    // leaky relu + partial (this wave's 16 cols) row sum-of-squares
    float p[4];
#pragma unroll
    for (int reg = 0; reg < 4; ++reg) {
      float x = acc[reg];
      x = (x >= 0.f) ? x : 0.01f * x;
      acc[reg] = x;
      p[reg] = x * x;
    }
#pragma unroll
    for (int off = 1; off < 16; off <<= 1) {
#pragma unroll
      for (int reg = 0; reg < 4; ++reg) p[reg] += __shfl_xor(p[reg], off, 64);
    }
    if (li == 0) {
#pragma unroll
      for (int reg = 0; reg < 4; ++reg) rsum[wv][4 * g + reg] = p[reg];
    }
  }
  __syncthreads();  // rsum ready

  if (wv < 4) {
    const int rowbase = blockIdx.x * 16;
    float* __restrict__ ob = out + (size_t)(layer + 1) * 64;
#pragma unroll
    for (int reg = 0; reg < 4; ++reg) {
      int rr = 4 * g + reg;
      float tot = rsum[0][rr] + rsum[1][rr] + rsum[2][rr] + rsum[3][rr];
      float inv = 1.0f / fmaxf(sqrtf(tot), 1e-12f);
      float val = acc[reg] * inv;
      ob[(size_t)(rowbase + rr) * 256 + wv * 16 + li] = val;
      if (wbf) ebf_next[(size_t)(rowbase + rr) * 64 + wv * 16 + li] = f2b(val);
    }
  }
}

extern "C" void kernel_launch(void* const* d_in, const int* in_sizes, int n_in,
                              void* d_out, int out_size, void* d_ws, size_t ws_size,
                              hipStream_t stream) {
  const int* edge_src = (const int*)d_in[0];
  const int* edge_dst = (const int*)d_in[1];
  const float* edge_w = (const float*)d_in[2];
  const float* user_emb = (const float*)d_in[3];
  const float* item_emb = (const float*)d_in[4];
  const float* Ws = (const float*)d_in[5];
  const float* bs = (const float*)d_in[6];
  float* out = (float*)d_out;

  char* w = (char*)d_ws;
  unsigned int* ebfA = (unsigned int*)w; w += (size_t)NN * 32 * 4;  // 25.6 MB
  unsigned int* ebfB = (unsigned int*)w; w += (size_t)NN * 32 * 4;  // 25.6 MB
  int2* csr_pack = (int2*)w;      w += (size_t)NE * 8;              // 10 MB
  unsigned short* WtBf = (unsigned short*)w; w += (size_t)3 * 64 * 192 * 2;
  int* cnt = (int*)w;             w += (size_t)NN * 4;
  int* local = (int*)w;           w += (size_t)NN * 4;
  int* row_start = (int*)w;       w += (size_t)(NN + 4) * 4;
  int* cursor = (int*)w;          w += (size_t)NN * 4;
  int* btot = (int*)w;            w += 256 * 4;

  k_zero<<<(NN + 255) / 256, 256, 0, stream>>>(cnt);
  k_setup_hist<<<SETUP_BLKS + HIST_BLKS, 256, 0, stream>>>(
      (const float4*)user_emb, (const float4*)item_emb, (float4*)out, (uint2*)ebfA,
      Ws, WtBf, edge_dst, cnt);
  k_scan1<<<NB, SCAN_B, 0, stream>>>(cnt, local, btot);
  k_scan2<<<1, 256, 0, stream>>>(btot);
  k_finalize<<<(NN + 255) / 256, 256, 0, stream>>>(local, btot, row_start, cursor);
  k_fill<<<(NE + 255) / 256, 256, 0, stream>>>(edge_src, edge_dst, edge_w, cursor, csr_pack);

  // layer l reads ebfX, writes ebfY (double-buffered: cross-block race otherwise)
  k_layer<<<NN / 16, 1024, 0, stream>>>(row_start, csr_pack, ebfA, WtBf, bs, out,
                                        (unsigned short*)ebfB, 0, 1);
  k_layer<<<NN / 16, 1024, 0, stream>>>(row_start, csr_pack, ebfB, WtBf, bs, out,
                                        (unsigned short*)ebfA, 1, 1);
  k_layer<<<NN / 16, 1024, 0, stream>>>(row_start, csr_pack, ebfA, WtBf, bs, out,
                                        (unsigned short*)ebfB, 2, 0);
}

// Round 10
// 430.089 us; speedup vs baseline: 1.2128x; 1.2128x over previous
//
#include <hip/hip_runtime.h>
#include <hip/hip_bf16.h>

#define NU 50000
#define NI 150000
#define NN 200000
#define NE 1250000
#define DD 64
#define NLAYERS 3
#define SCAN_B 1024
#define NB ((NN + SCAN_B - 1) / SCAN_B)   // 196
#define BT_STRIDE 232                      // bf16; 464B row: 16B-aligned, <=2-way banks on frag reads

typedef __attribute__((ext_vector_type(8))) short bf16x8;
typedef __attribute__((ext_vector_type(4))) float f32x4;

static __device__ __forceinline__ unsigned short f2b(float x) {
  __hip_bfloat16 h = __float2bfloat16(x);  // RNE
  return *reinterpret_cast<unsigned short*>(&h);
}

static __device__ __forceinline__ unsigned int pack2(float lo, float hi) {
  return (unsigned int)f2b(lo) | ((unsigned int)f2b(hi) << 16);
}

static __device__ __forceinline__ float blo(unsigned int u) { return __uint_as_float(u << 16); }
static __device__ __forceinline__ float bhi(unsigned int u) { return __uint_as_float(u & 0xffff0000u); }

// elementwise bf16x8 * bf16x8 -> bf16x8 (via f32)
static __device__ __forceinline__ bf16x8 mulbf8(bf16x8 a, bf16x8 b) {
  union { bf16x8 v; unsigned int u[4]; } A, B, R;
  A.v = a; B.v = b;
#pragma unroll
  for (int i = 0; i < 4; ++i) {
    R.u[i] = pack2(blo(A.u[i]) * blo(B.u[i]), bhi(A.u[i]) * bhi(B.u[i]));
  }
  return R.v;
}

// ---- merged setup: init out/ebf + zero cnt + W^T bf16 prep (R8-proven) ----
__global__ __launch_bounds__(256) void k_setup(const float4* __restrict__ ue,
                                               const float4* __restrict__ ie,
                                               float4* __restrict__ out4,
                                               uint2* __restrict__ ebf2,
                                               const float* __restrict__ Ws,
                                               unsigned short* __restrict__ WtBf,
                                               int* __restrict__ cnt) {
  int gid = blockIdx.x * 256 + threadIdx.x;
  if (gid < NN * 16) {
    int row = gid >> 4, q = gid & 15;
    float4 v = (row < NU) ? ue[(size_t)row * 16 + q] : ie[(size_t)(row - NU) * 16 + q];
    out4[(size_t)row * 64 + q] = v;  // out row stride = 256 floats = 64 float4
    uint2 b; b.x = pack2(v.x, v.y); b.y = pack2(v.z, v.w);
    ebf2[(size_t)row * 16 + q] = b;  // ebf row = 64 bf16 = 16 uint2
  }
  if (gid < NN) cnt[gid] = 0;
  if (gid < 3 * 64 * 192) {
    int j = gid % 192;
    int n = (gid / 192) & 63;
    int lyr = gid / (192 * 64);
    WtBf[gid] = f2b(Ws[((size_t)lyr * 3 + (j >> 6)) * 4096 + (size_t)(j & 63) * 64 + n]);
  }
}

// ---- CSR build ----
__global__ __launch_bounds__(256) void k_hist(const int* __restrict__ dst, int* __restrict__ cnt) {
  int e = blockIdx.x * 256 + threadIdx.x;
  if (e < NE) atomicAdd(&cnt[dst[e]], 1);
}

__global__ __launch_bounds__(SCAN_B) void k_scan1(const int* __restrict__ cnt,
                                                  int* __restrict__ local,
                                                  int* __restrict__ btot) {
  __shared__ int sm[SCAN_B];
  int t = threadIdx.x;
  int i = blockIdx.x * SCAN_B + t;
  int v = (i < NN) ? cnt[i] : 0;
  sm[t] = v;
  __syncthreads();
  for (int off = 1; off < SCAN_B; off <<= 1) {
    int x = (t >= off) ? sm[t - off] : 0;
    __syncthreads();
    sm[t] += x;
    __syncthreads();
  }
  if (i < NN) local[i] = sm[t] - v;              // exclusive within block
  if (t == SCAN_B - 1) btot[blockIdx.x] = sm[t]; // block total
}

__global__ __launch_bounds__(256) void k_scan2(int* __restrict__ btot) {
  __shared__ int sm[256];
  int t = threadIdx.x;
  int v = (t < NB) ? btot[t] : 0;
  sm[t] = v;
  __syncthreads();
  for (int off = 1; off < 256; off <<= 1) {
    int x = (t >= off) ? sm[t - off] : 0;
    __syncthreads();
    sm[t] += x;
    __syncthreads();
  }
  if (t < NB) btot[t] = sm[t] - v;  // exclusive block offsets
}

__global__ __launch_bounds__(256) void k_finalize(const int* __restrict__ local,
                                                  const int* __restrict__ btot,
                                                  int* __restrict__ row_start,
                                                  int* __restrict__ cursor) {
  int i = blockIdx.x * 256 + threadIdx.x;
  if (i < NN) {
    int v = local[i] + btot[i / SCAN_B];
    row_start[i] = v;
    cursor[i] = v;
  }
  if (i == 0) row_start[NN] = NE;
}

__global__ __launch_bounds__(256) void k_fill(const int* __restrict__ src,
                                              const int* __restrict__ dst,
                                              const float* __restrict__ w,
                                              int* __restrict__ cursor,
                                              int2* __restrict__ csr_pack) {
  int e = blockIdx.x * 256 + threadIdx.x;
  if (e < NE) {
    int p = atomicAdd(&cursor[dst[e]], 1);
    int2 pk; pk.x = src[e]; pk.y = __float_as_int(w[e]);
    csr_pack[p] = pk;
  }
}

// ---- fused layer v2: 512 thr = 8 waves; each wave gathers 4 rows (serial, service-rate-
//      bound so cheap); LDS t1 tile [32][72]; then BALANCED MFMA: 2 tiles x 4 col-blocks
//      = 8 waves all active; cross-wave l2norm via rsum LDS ----
// grid = 6250 (NN/32 exact); LDS 34.3KB -> 4 blocks/CU = 32 waves/CU
__global__ __launch_bounds__(512, 8) void k_fused(const int* __restrict__ row_start,
                                                  const int2* __restrict__ csr_pack,
                                                  const unsigned int* __restrict__ ebf,   // [NN][32] uint
                                                  const unsigned short* __restrict__ WtBf,
                                                  const float* __restrict__ bs,
                                                  float* __restrict__ out,
                                                  unsigned short* __restrict__ ebf_next,
                                                  int layer, int wbf) {
  __shared__ unsigned short Bt[64][BT_STRIDE];  // Bt[n][j] = bf16(Wcat[j][n])
  __shared__ unsigned short t1s[32][72];        // t1 tile, 144B stride (16B-aligned, 2-way free)
  __shared__ float rsum[2][4][16];              // [tile][colblock][row]

  const int tid = threadIdx.x;
  const int wv = tid >> 6;
  const int l = tid & 63;
  const int rbase = blockIdx.x * 32;

  {  // stage 24KB Bt tile, fully coalesced (3 uint4/thread)
    const uint4* __restrict__ src = reinterpret_cast<const uint4*>(WtBf + (size_t)layer * 64 * 192);
#pragma unroll
    for (int ch = tid; ch < 1536; ch += 512) {
      int rown = ch / 24, k = ch % 24;
      *reinterpret_cast<uint4*>(&Bt[rown][k * 8]) = src[ch];
    }
  }

  // ===== gather phase: 4 rows per wave =====
  {
    const int eidx = l >> 3;
    const int cb = l & 7;
#pragma unroll 1
    for (int i = 0; i < 4; ++i) {
      const int row = rbase + wv * 4 + i;
      int s0 = row_start[row];
      int s1 = row_start[row + 1];
      int deg = s1 - s0;  // wave-uniform

      float a0 = 0.f, a1 = 0.f, a2 = 0.f, a3 = 0.f, a4 = 0.f, a5 = 0.f, a6 = 0.f, a7 = 0.f;

      if (deg > 0) {
        int j0 = s0 + eidx;
        bool e0 = j0 < s1;
        j0 = e0 ? j0 : s1 - 1;
        int2 p0 = csr_pack[j0];
        uint4 v0 = *reinterpret_cast<const uint4*>(ebf + (size_t)p0.x * 32 + cb * 4);
        float w0 = e0 ? __int_as_float(p0.y) : 0.f;
        if (deg > 8) {
          int j1 = s0 + 8 + eidx;
          bool e1 = j1 < s1;
          j1 = e1 ? j1 : s1 - 1;
          int2 p1 = csr_pack[j1];
          uint4 v1 = *reinterpret_cast<const uint4*>(ebf + (size_t)p1.x * 32 + cb * 4);
          float w1 = e1 ? __int_as_float(p1.y) : 0.f;
          a0 = fmaf(w0, blo(v0.x), a0); a1 = fmaf(w0, bhi(v0.x), a1);
          a2 = fmaf(w0, blo(v0.y), a2); a3 = fmaf(w0, bhi(v0.y), a3);
          a4 = fmaf(w0, blo(v0.z), a4); a5 = fmaf(w0, bhi(v0.z), a5);
          a6 = fmaf(w0, blo(v0.w), a6); a7 = fmaf(w0, bhi(v0.w), a7);
          a0 = fmaf(w1, blo(v1.x), a0); a1 = fmaf(w1, bhi(v1.x), a1);
          a2 = fmaf(w1, blo(v1.y), a2); a3 = fmaf(w1, bhi(v1.y), a3);
          a4 = fmaf(w1, blo(v1.z), a4); a5 = fmaf(w1, bhi(v1.z), a5);
          a6 = fmaf(w1, blo(v1.w), a6); a7 = fmaf(w1, bhi(v1.w), a7);
          for (int base = s0 + 16; base < s1; base += 8) {  // deg>16: ~0.3%
            int j = base + eidx;
            bool ev = j < s1;
            j = ev ? j : s1 - 1;
            int2 p = csr_pack[j];
            uint4 v = *reinterpret_cast<const uint4*>(ebf + (size_t)p.x * 32 + cb * 4);
            float wt = ev ? __int_as_float(p.y) : 0.f;
            a0 = fmaf(wt, blo(v.x), a0); a1 = fmaf(wt, bhi(v.x), a1);
            a2 = fmaf(wt, blo(v.y), a2); a3 = fmaf(wt, bhi(v.y), a3);
            a4 = fmaf(wt, blo(v.z), a4); a5 = fmaf(wt, bhi(v.z), a5);
            a6 = fmaf(wt, blo(v.w), a6); a7 = fmaf(wt, bhi(v.w), a7);
          }
        } else {
          a0 = fmaf(w0, blo(v0.x), a0); a1 = fmaf(w0, bhi(v0.x), a1);
          a2 = fmaf(w0, blo(v0.y), a2); a3 = fmaf(w0, bhi(v0.y), a3);
          a4 = fmaf(w0, blo(v0.z), a4); a5 = fmaf(w0, bhi(v0.z), a5);
          a6 = fmaf(w0, blo(v0.w), a6); a7 = fmaf(w0, bhi(v0.w), a7);
        }
      }

      a0 += __shfl_xor(a0, 8, 64);  a0 += __shfl_xor(a0, 16, 64);  a0 += __shfl_xor(a0, 32, 64);
      a1 += __shfl_xor(a1, 8, 64);  a1 += __shfl_xor(a1, 16, 64);  a1 += __shfl_xor(a1, 32, 64);
      a2 += __shfl_xor(a2, 8, 64);  a2 += __shfl_xor(a2, 16, 64);  a2 += __shfl_xor(a2, 32, 64);
      a3 += __shfl_xor(a3, 8, 64);  a3 += __shfl_xor(a3, 16, 64);  a3 += __shfl_xor(a3, 32, 64);
      a4 += __shfl_xor(a4, 8, 64);  a4 += __shfl_xor(a4, 16, 64);  a4 += __shfl_xor(a4, 32, 64);
      a5 += __shfl_xor(a5, 8, 64);  a5 += __shfl_xor(a5, 16, 64);  a5 += __shfl_xor(a5, 32, 64);
      a6 += __shfl_xor(a6, 8, 64);  a6 += __shfl_xor(a6, 16, 64);  a6 += __shfl_xor(a6, 32, 64);
      a7 += __shfl_xor(a7, 8, 64);  a7 += __shfl_xor(a7, 16, 64);  a7 += __shfl_xor(a7, 32, 64);

      if (l < 8) {
        uint4 st;
        st.x = pack2(a0, a1); st.y = pack2(a2, a3); st.z = pack2(a4, a5); st.w = pack2(a6, a7);
        *reinterpret_cast<uint4*>(&t1s[wv * 4 + i][l * 8]) = st;
      }
    }
  }
  __syncthreads();  // t1 tile + Bt ready

  // ===== MFMA phase: wave wv -> tile t = wv>>2 (rows t*16..+15), colblock f = wv&3 =====
  const int t = wv >> 2;
  const int f = wv & 3;
  const int g = l >> 4;    // A: k-group; D: row-group
  const int li = l & 15;   // A: row; D: col-within-block
  const int r = rbase + t * 16 + li;

  bf16x8 A0 = *reinterpret_cast<const bf16x8*>(&t1s[t * 16 + li][8 * g]);
  bf16x8 A1 = *reinterpret_cast<const bf16x8*>(&t1s[t * 16 + li][32 + 8 * g]);
  const unsigned short* __restrict__ eb = reinterpret_cast<const unsigned short*>(ebf);
  bf16x8 E0 = *reinterpret_cast<const bf16x8*>(eb + (size_t)r * 64 + 8 * g);
  bf16x8 E1 = *reinterpret_cast<const bf16x8*>(eb + (size_t)r * 64 + 32 + 8 * g);
  bf16x8 T0 = mulbf8(A0, E0);
  bf16x8 T1 = mulbf8(A1, E1);

  const float* __restrict__ bsl = bs + (size_t)layer * 3 * 64;
  const int n = f * 16 + li;
  float bv = bsl[n] + bsl[64 + n] + bsl[128 + n];
  f32x4 acc = (f32x4){bv, bv, bv, bv};

  bf16x8 Afr[6] = {A0, A1, T0, T1, E0, E1};
#pragma unroll
  for (int s = 0; s < 6; ++s) {
    const bf16x8 Bf = *reinterpret_cast<const bf16x8*>(&Bt[f * 16 + li][s * 32 + 8 * g]);
    acc = __builtin_amdgcn_mfma_f32_16x16x32_bf16(Afr[s], Bf, acc, 0, 0, 0);
  }

  // leaky relu + partial (this wave's 16 cols) row sum-of-squares
  float p[4];
#pragma unroll
  for (int reg = 0; reg < 4; ++reg) {
    float x = acc[reg];
    x = (x >= 0.f) ? x : 0.01f * x;
    acc[reg] = x;
    p[reg] = x * x;
  }
#pragma unroll
  for (int off = 1; off < 16; off <<= 1) {
#pragma unroll
    for (int reg = 0; reg < 4; ++reg) p[reg] += __shfl_xor(p[reg], off, 64);
  }
  if (li == 0) {
#pragma unroll
    for (int reg = 0; reg < 4; ++reg) rsum[t][f][4 * g + reg] = p[reg];
  }
  __syncthreads();  // rsum ready

  float* __restrict__ ob = out + (size_t)(layer + 1) * 64;
#pragma unroll
  for (int reg = 0; reg < 4; ++reg) {
    int rr = 4 * g + reg;
    float tot = rsum[t][0][rr] + rsum[t][1][rr] + rsum[t][2][rr] + rsum[t][3][rr];
    float inv = 1.0f / fmaxf(sqrtf(tot), 1e-12f);
    float val = acc[reg] * inv;
    ob[(size_t)(rbase + t * 16 + rr) * 256 + f * 16 + li] = val;
    if (wbf) ebf_next[(size_t)(rbase + t * 16 + rr) * 64 + f * 16 + li] = f2b(val);
  }
}

extern "C" void kernel_launch(void* const* d_in, const int* in_sizes, int n_in,
                              void* d_out, int out_size, void* d_ws, size_t ws_size,
                              hipStream_t stream) {
  const int* edge_src = (const int*)d_in[0];
  const int* edge_dst = (const int*)d_in[1];
  const float* edge_w = (const float*)d_in[2];
  const float* user_emb = (const float*)d_in[3];
  const float* item_emb = (const float*)d_in[4];
  const float* Ws = (const float*)d_in[5];
  const float* bs = (const float*)d_in[6];
  float* out = (float*)d_out;

  char* w = (char*)d_ws;
  unsigned int* ebfA = (unsigned int*)w; w += (size_t)NN * 32 * 4;  // 25.6 MB
  unsigned int* ebfB = (unsigned int*)w; w += (size_t)NN * 32 * 4;  // 25.6 MB
  int2* csr_pack = (int2*)w;      w += (size_t)NE * 8;              // 10 MB
  unsigned short* WtBf = (unsigned short*)w; w += (size_t)3 * 64 * 192 * 2;
  int* cnt = (int*)w;             w += (size_t)NN * 4;
  int* local = (int*)w;           w += (size_t)NN * 4;
  int* row_start = (int*)w;       w += (size_t)(NN + 4) * 4;
  int* cursor = (int*)w;          w += (size_t)NN * 4;
  int* btot = (int*)w;            w += 256 * 4;

  k_setup<<<(NN * 16 + 255) / 256, 256, 0, stream>>>(
      (const float4*)user_emb, (const float4*)item_emb, (float4*)out, (uint2*)ebfA,
      Ws, WtBf, cnt);
  k_hist<<<(NE + 255) / 256, 256, 0, stream>>>(edge_dst, cnt);
  k_scan1<<<NB, SCAN_B, 0, stream>>>(cnt, local, btot);
  k_scan2<<<1, 256, 0, stream>>>(btot);
  k_finalize<<<(NN + 255) / 256, 256, 0, stream>>>(local, btot, row_start, cursor);
  k_fill<<<(NE + 255) / 256, 256, 0, stream>>>(edge_src, edge_dst, edge_w, cursor, csr_pack);

  // layer l reads ebfX, writes ebfY (double-buffered: cross-block race otherwise)
  k_fused<<<NN / 32, 512, 0, stream>>>(row_start, csr_pack, ebfA, WtBf, bs, out,
                                       (unsigned short*)ebfB, 0, 1);
  k_fused<<<NN / 32, 512, 0, stream>>>(row_start, csr_pack, ebfB, WtBf, bs, out,
                                       (unsigned short*)ebfA, 1, 1);
  k_fused<<<NN / 32, 512, 0, stream>>>(row_start, csr_pack, ebfA, WtBf, bs, out,
                                       (unsigned short*)ebfB, 2, 0);
}

// Round 11
// 401.817 us; speedup vs baseline: 1.2982x; 1.0704x over previous
//
#include <hip/hip_runtime.h>
#include <hip/hip_bf16.h>

#define NU 50000
#define NI 150000
#define NN 200000
#define NE 1250000
#define DD 64
#define NLAYERS 3
#define SCAN_B 1024
#define NB ((NN + SCAN_B - 1) / SCAN_B)   // 196
#define BT_STRIDE 232                      // bf16; 464B row: 16B-aligned, <=2-way banks on frag reads
#define SETUP_BLKS 12500                   // NN*16/256
#define HIST_BLKS ((NE + 255) / 256)       // 4883

typedef __attribute__((ext_vector_type(8))) short bf16x8;
typedef __attribute__((ext_vector_type(4))) float f32x4;

static __device__ __forceinline__ unsigned short f2b(float x) {
  __hip_bfloat16 h = __float2bfloat16(x);  // RNE
  return *reinterpret_cast<unsigned short*>(&h);
}

static __device__ __forceinline__ unsigned int pack2(float lo, float hi) {
  return (unsigned int)f2b(lo) | ((unsigned int)f2b(hi) << 16);
}

static __device__ __forceinline__ float blo(unsigned int u) { return __uint_as_float(u << 16); }
static __device__ __forceinline__ float bhi(unsigned int u) { return __uint_as_float(u & 0xffff0000u); }

// elementwise bf16x8 * bf16x8 -> bf16x8 (via f32)
static __device__ __forceinline__ bf16x8 mulbf8(bf16x8 a, bf16x8 b) {
  union { bf16x8 v; unsigned int u[4]; } A, B, R;
  A.v = a; B.v = b;
#pragma unroll
  for (int i = 0; i < 4; ++i) {
    R.u[i] = pack2(blo(A.u[i]) * blo(B.u[i]), bhi(A.u[i]) * bhi(B.u[i]));
  }
  return R.v;
}

// ---- zero cnt (must precede merged setup+hist) ----
__global__ __launch_bounds__(256) void k_zero(int* __restrict__ p) {
  int i = blockIdx.x * 256 + threadIdx.x;
  if (i < NN) p[i] = 0;
}

// ---- merged: init out/ebf + W^T prep (blocks < SETUP_BLKS) | histogram (rest) ----
// Independent data -> the small atomic-bound hist hides under the streaming init.
__global__ __launch_bounds__(256) void k_setup_hist(const float4* __restrict__ ue,
                                                    const float4* __restrict__ ie,
                                                    float4* __restrict__ out4,
                                                    uint2* __restrict__ ebf2,
                                                    const float* __restrict__ Ws,
                                                    unsigned short* __restrict__ WtBf,
                                                    const int* __restrict__ dst,
                                                    int* __restrict__ cnt) {
  int bid = blockIdx.x;
  if (bid < SETUP_BLKS) {
    int gid = bid * 256 + threadIdx.x;  // < NN*16 exactly
    int row = gid >> 4, q = gid & 15;
    float4 v = (row < NU) ? ue[(size_t)row * 16 + q] : ie[(size_t)(row - NU) * 16 + q];
    out4[(size_t)row * 64 + q] = v;  // out row stride = 256 floats = 64 float4
    uint2 b; b.x = pack2(v.x, v.y); b.y = pack2(v.z, v.w);
    ebf2[(size_t)row * 16 + q] = b;  // ebf row = 64 bf16 = 16 uint2
    if (gid < 3 * 64 * 192) {
      int j = gid % 192;
      int n = (gid / 192) & 63;
      int lyr = gid / (192 * 64);
      WtBf[gid] = f2b(Ws[((size_t)lyr * 3 + (j >> 6)) * 4096 + (size_t)(j & 63) * 64 + n]);
    }
  } else {
    int e = (bid - SETUP_BLKS) * 256 + threadIdx.x;
    if (e < NE) atomicAdd(&cnt[dst[e]], 1);
  }
}

__global__ __launch_bounds__(SCAN_B) void k_scan1(const int* __restrict__ cnt,
                                                  int* __restrict__ local,
                                                  int* __restrict__ btot) {
  __shared__ int sm[SCAN_B];
  int t = threadIdx.x;
  int i = blockIdx.x * SCAN_B + t;
  int v = (i < NN) ? cnt[i] : 0;
  sm[t] = v;
  __syncthreads();
  for (int off = 1; off < SCAN_B; off <<= 1) {
    int x = (t >= off) ? sm[t - off] : 0;
    __syncthreads();
    sm[t] += x;
    __syncthreads();
  }
  if (i < NN) local[i] = sm[t] - v;              // exclusive within block
  if (t == SCAN_B - 1) btot[blockIdx.x] = sm[t]; // block total
}

__global__ __launch_bounds__(256) void k_scan2(int* __restrict__ btot) {
  __shared__ int sm[256];
  int t = threadIdx.x;
  int v = (t < NB) ? btot[t] : 0;
  sm[t] = v;
  __syncthreads();
  for (int off = 1; off < 256; off <<= 1) {
    int x = (t >= off) ? sm[t - off] : 0;
    __syncthreads();
    sm[t] += x;
    __syncthreads();
  }
  if (t < NB) btot[t] = sm[t] - v;  // exclusive block offsets
}

__global__ __launch_bounds__(256) void k_finalize(const int* __restrict__ local,
                                                  const int* __restrict__ btot,
                                                  int* __restrict__ row_start,
                                                  int* __restrict__ cursor) {
  int i = blockIdx.x * 256 + threadIdx.x;
  if (i < NN) {
    int v = local[i] + btot[i / SCAN_B];
    row_start[i] = v;
    cursor[i] = v;
  }
  if (i == 0) row_start[NN] = NE;
}

__global__ __launch_bounds__(256) void k_fill(const int* __restrict__ src,
                                              const int* __restrict__ dst,
                                              const float* __restrict__ w,
                                              int* __restrict__ cursor,
                                              int2* __restrict__ csr_pack) {
  int e = blockIdx.x * 256 + threadIdx.x;
  if (e < NE) {
    int p = atomicAdd(&cursor[dst[e]], 1);
    int2 pk; pk.x = src[e]; pk.y = __float_as_int(w[e]);
    csr_pack[p] = pk;
  }
}

// ---- SpMM v4 (R8-proven): one wave per row; 8 lanes x uint4 per edge row;
//      uniform round-2 skip; dead slots clamp to s1-1 (no extra cache lines) ----
__global__ __launch_bounds__(256) void k_spmm(const int* __restrict__ row_start,
                                              const int2* __restrict__ csr_pack,
                                              const unsigned int* __restrict__ ebf, // [NN][32] uint (64 bf16)
                                              unsigned int* __restrict__ t1bf) {   // [NN][32] uint (64 bf16)
  int gid = blockIdx.x * 256 + threadIdx.x;
  int row = gid >> 6;
  if (row >= NN) return;
  const int l = gid & 63;
  const int eidx = l >> 3;
  const int cb = l & 7;
  int s0 = row_start[row];
  int s1 = row_start[row + 1];
  int deg = s1 - s0;  // wave-uniform

  float a0 = 0.f, a1 = 0.f, a2 = 0.f, a3 = 0.f, a4 = 0.f, a5 = 0.f, a6 = 0.f, a7 = 0.f;

  if (deg > 0) {
    int j0 = s0 + eidx;
    bool e0 = j0 < s1;
    j0 = e0 ? j0 : s1 - 1;
    int2 p0 = csr_pack[j0];
    uint4 v0 = *reinterpret_cast<const uint4*>(ebf + (size_t)p0.x * 32 + cb * 4);
    float w0 = e0 ? __int_as_float(p0.y) : 0.f;
    if (deg > 8) {
      int j1 = s0 + 8 + eidx;
      bool e1 = j1 < s1;
      j1 = e1 ? j1 : s1 - 1;
      int2 p1 = csr_pack[j1];
      uint4 v1 = *reinterpret_cast<const uint4*>(ebf + (size_t)p1.x * 32 + cb * 4);
      float w1 = e1 ? __int_as_float(p1.y) : 0.f;
      a0 = fmaf(w0, blo(v0.x), a0); a1 = fmaf(w0, bhi(v0.x), a1);
      a2 = fmaf(w0, blo(v0.y), a2); a3 = fmaf(w0, bhi(v0.y), a3);
      a4 = fmaf(w0, blo(v0.z), a4); a5 = fmaf(w0, bhi(v0.z), a5);
      a6 = fmaf(w0, blo(v0.w), a6); a7 = fmaf(w0, bhi(v0.w), a7);
      a0 = fmaf(w1, blo(v1.x), a0); a1 = fmaf(w1, bhi(v1.x), a1);
      a2 = fmaf(w1, blo(v1.y), a2); a3 = fmaf(w1, bhi(v1.y), a3);
      a4 = fmaf(w1, blo(v1.z), a4); a5 = fmaf(w1, bhi(v1.z), a5);
      a6 = fmaf(w1, blo(v1.w), a6); a7 = fmaf(w1, bhi(v1.w), a7);
      for (int base = s0 + 16; base < s1; base += 8) {  // deg>16: ~0.3% of rows
        int j = base + eidx;
        bool ev = j < s1;
        j = ev ? j : s1 - 1;
        int2 p = csr_pack[j];
        uint4 v = *reinterpret_cast<const uint4*>(ebf + (size_t)p.x * 32 + cb * 4);
        float wt = ev ? __int_as_float(p.y) : 0.f;
        a0 = fmaf(wt, blo(v.x), a0); a1 = fmaf(wt, bhi(v.x), a1);
        a2 = fmaf(wt, blo(v.y), a2); a3 = fmaf(wt, bhi(v.y), a3);
        a4 = fmaf(wt, blo(v.z), a4); a5 = fmaf(wt, bhi(v.z), a5);
        a6 = fmaf(wt, blo(v.w), a6); a7 = fmaf(wt, bhi(v.w), a7);
      }
    } else {
      a0 = fmaf(w0, blo(v0.x), a0); a1 = fmaf(w0, bhi(v0.x), a1);
      a2 = fmaf(w0, blo(v0.y), a2); a3 = fmaf(w0, bhi(v0.y), a3);
      a4 = fmaf(w0, blo(v0.z), a4); a5 = fmaf(w0, bhi(v0.z), a5);
      a6 = fmaf(w0, blo(v0.w), a6); a7 = fmaf(w0, bhi(v0.w), a7);
    }
  }

  a0 += __shfl_xor(a0, 8, 64);  a0 += __shfl_xor(a0, 16, 64);  a0 += __shfl_xor(a0, 32, 64);
  a1 += __shfl_xor(a1, 8, 64);  a1 += __shfl_xor(a1, 16, 64);  a1 += __shfl_xor(a1, 32, 64);
  a2 += __shfl_xor(a2, 8, 64);  a2 += __shfl_xor(a2, 16, 64);  a2 += __shfl_xor(a2, 32, 64);
  a3 += __shfl_xor(a3, 8, 64);  a3 += __shfl_xor(a3, 16, 64);  a3 += __shfl_xor(a3, 32, 64);
  a4 += __shfl_xor(a4, 8, 64);  a4 += __shfl_xor(a4, 16, 64);  a4 += __shfl_xor(a4, 32, 64);
  a5 += __shfl_xor(a5, 8, 64);  a5 += __shfl_xor(a5, 16, 64);  a5 += __shfl_xor(a5, 32, 64);
  a6 += __shfl_xor(a6, 8, 64);  a6 += __shfl_xor(a6, 16, 64);  a6 += __shfl_xor(a6, 32, 64);
  a7 += __shfl_xor(a7, 8, 64);  a7 += __shfl_xor(a7, 16, 64);  a7 += __shfl_xor(a7, 32, 64);

  if (l < 8) {  // lane cb==l stores cols 8l..8l+7: 8 lanes x 16B = coalesced 128B row
    uint4 st;
    st.x = pack2(a0, a1); st.y = pack2(a2, a3); st.z = pack2(a4, a5); st.w = pack2(a6, a7);
    *reinterpret_cast<uint4*>(t1bf + (size_t)row * 32 + l * 4) = st;
  }
}

// ---- GEMM via MFMA (R8-proven): inter = [t1 | t1*e | e] @ [W1;W2;W3] + b; leaky; l2norm ----
// wave = 16 rows; block = 8 waves = 128 rows; grid = 1563
__global__ __launch_bounds__(512) void k_row_mfma(const unsigned int* __restrict__ t1bf,
                                                  const unsigned int* __restrict__ ebf,
                                                  const unsigned short* __restrict__ WtBf,
                                                  const float* __restrict__ bs,
                                                  float* __restrict__ out,
                                                  unsigned short* __restrict__ ebf_next,
                                                  int layer, int wbf) {
  __shared__ unsigned short Bt[64][BT_STRIDE];  // Bt[n][j] = bf16(Wcat[j][n]), j in [0,192)
  const int tid = threadIdx.x;
  {
    // stage 64x192 bf16 tile (24KB) from prepacked global: fully coalesced uint4 copies
    const uint4* __restrict__ src = reinterpret_cast<const uint4*>(WtBf + (size_t)layer * 64 * 192);
#pragma unroll
    for (int ch = tid; ch < 1536; ch += 512) {
      int rown = ch / 24, k = ch % 24;
      *reinterpret_cast<uint4*>(&Bt[rown][k * 8]) = src[ch];
    }
  }
  __syncthreads();

  const int l = tid & 63;
  const int wv = tid >> 6;
  const int g = l >> 4;    // A: k-group; D: row-group
  const int li = l & 15;   // A: row; D: col
  const int rowbase = blockIdx.x * 128 + wv * 16;
  if (rowbase >= NN) return;
  const int r = rowbase + li;

  // A fragments straight from bf16 buffers: lane holds 8 contiguous k at 8*g / 32+8*g
  const unsigned short* __restrict__ t1b = reinterpret_cast<const unsigned short*>(t1bf);
  const unsigned short* __restrict__ eb = reinterpret_cast<const unsigned short*>(ebf);
  bf16x8 A0 = *reinterpret_cast<const bf16x8*>(t1b + (size_t)r * 64 + 8 * g);
  bf16x8 A1 = *reinterpret_cast<const bf16x8*>(t1b + (size_t)r * 64 + 32 + 8 * g);
  bf16x8 E0 = *reinterpret_cast<const bf16x8*>(eb + (size_t)r * 64 + 8 * g);
  bf16x8 E1 = *reinterpret_cast<const bf16x8*>(eb + (size_t)r * 64 + 32 + 8 * g);
  bf16x8 T0 = mulbf8(A0, E0);
  bf16x8 T1 = mulbf8(A1, E1);

  const float* __restrict__ bsl = bs + (size_t)layer * 3 * 64;
  f32x4 acc[4];
#pragma unroll
  for (int f = 0; f < 4; ++f) {
    int n = f * 16 + li;
    float bv = bsl[n] + bsl[64 + n] + bsl[128 + n];
    acc[f] = (f32x4){bv, bv, bv, bv};
  }

  bf16x8 Afr[6] = {A0, A1, T0, T1, E0, E1};
#pragma unroll
  for (int s = 0; s < 6; ++s) {
#pragma unroll
    for (int f = 0; f < 4; ++f) {
      const bf16x8 Bf = *reinterpret_cast<const bf16x8*>(&Bt[f * 16 + li][s * 32 + 8 * g]);
      acc[f] = __builtin_amdgcn_mfma_f32_16x16x32_bf16(Afr[s], Bf, acc[f], 0, 0, 0);
    }
  }

  // epilogue: leaky relu, row L2 norm (row = rowbase + 4*g + reg, col = f*16 + li)
  float p[4];
#pragma unroll
  for (int reg = 0; reg < 4; ++reg) {
    float ssum = 0.f;
#pragma unroll
    for (int f = 0; f < 4; ++f) {
      float x = acc[f][reg];
      x = (x >= 0.f) ? x : 0.01f * x;
      acc[f][reg] = x;
      ssum = fmaf(x, x, ssum);
    }
    p[reg] = ssum;
  }
#pragma unroll
  for (int off = 1; off < 16; off <<= 1) {
#pragma unroll
    for (int reg = 0; reg < 4; ++reg) p[reg] += __shfl_xor(p[reg], off, 64);
  }
  float inv[4];
#pragma unroll
  for (int reg = 0; reg < 4; ++reg) inv[reg] = 1.0f / fmaxf(sqrtf(p[reg]), 1e-12f);

  float* __restrict__ ob = out + (size_t)(layer + 1) * 64;
#pragma unroll
  for (int reg = 0; reg < 4; ++reg) {
#pragma unroll
    for (int f = 0; f < 4; ++f) {
      float val = acc[f][reg] * inv[reg];
      ob[(size_t)(rowbase + 4 * g + reg) * 256 + f * 16 + li] = val;
      if (wbf) ebf_next[(size_t)(rowbase + 4 * g + reg) * 64 + f * 16 + li] = f2b(val);
    }
  }
}

extern "C" void kernel_launch(void* const* d_in, const int* in_sizes, int n_in,
                              void* d_out, int out_size, void* d_ws, size_t ws_size,
                              hipStream_t stream) {
  const int* edge_src = (const int*)d_in[0];
  const int* edge_dst = (const int*)d_in[1];
  const float* edge_w = (const float*)d_in[2];
  const float* user_emb = (const float*)d_in[3];
  const float* item_emb = (const float*)d_in[4];
  const float* Ws = (const float*)d_in[5];
  const float* bs = (const float*)d_in[6];
  float* out = (float*)d_out;

  char* w = (char*)d_ws;
  unsigned int* ebfA = (unsigned int*)w; w += (size_t)NN * 32 * 4;  // 25.6 MB
  unsigned int* ebfB = (unsigned int*)w; w += (size_t)NN * 32 * 4;  // 25.6 MB
  unsigned int* t1bf = (unsigned int*)w; w += (size_t)NN * 32 * 4;  // 25.6 MB
  int2* csr_pack = (int2*)w;      w += (size_t)NE * 8;              // 10 MB
  unsigned short* WtBf = (unsigned short*)w; w += (size_t)3 * 64 * 192 * 2;
  int* cnt = (int*)w;             w += (size_t)NN * 4;
  int* local = (int*)w;           w += (size_t)NN * 4;
  int* row_start = (int*)w;       w += (size_t)(NN + 4) * 4;
  int* cursor = (int*)w;          w += (size_t)NN * 4;
  int* btot = (int*)w;            w += 256 * 4;

  k_zero<<<(NN + 255) / 256, 256, 0, stream>>>(cnt);
  k_setup_hist<<<SETUP_BLKS + HIST_BLKS, 256, 0, stream>>>(
      (const float4*)user_emb, (const float4*)item_emb, (float4*)out, (uint2*)ebfA,
      Ws, WtBf, edge_dst, cnt);
  k_scan1<<<NB, SCAN_B, 0, stream>>>(cnt, local, btot);
  k_scan2<<<1, 256, 0, stream>>>(btot);
  k_finalize<<<(NN + 255) / 256, 256, 0, stream>>>(local, btot, row_start, cursor);
  k_fill<<<(NE + 255) / 256, 256, 0, stream>>>(edge_src, edge_dst, edge_w, cursor, csr_pack);

  // layer l reads ebfX, writes ebfY (double-buffered: cross-block race otherwise)
  k_spmm<<<(NN * 64 + 255) / 256, 256, 0, stream>>>(row_start, csr_pack, ebfA, t1bf);
  k_row_mfma<<<(NN + 127) / 128, 512, 0, stream>>>(t1bf, ebfA, WtBf, bs, out, (unsigned short*)ebfB, 0, 1);
  k_spmm<<<(NN * 64 + 255) / 256, 256, 0, stream>>>(row_start, csr_pack, ebfB, t1bf);
  k_row_mfma<<<(NN + 127) / 128, 512, 0, stream>>>(t1bf, ebfB, WtBf, bs, out, (unsigned short*)ebfA, 1, 1);
  k_spmm<<<(NN * 64 + 255) / 256, 256, 0, stream>>>(row_start, csr_pack, ebfA, t1bf);
  k_row_mfma<<<(NN + 127) / 128, 512, 0, stream>>>(t1bf, ebfA, WtBf, bs, out, (unsigned short*)ebfB, 2, 0);
}